// Round 1
// baseline (19697.351 us; speedup 1.0000x reference)
//
#include <hip/hip_runtime.h>

typedef __attribute__((ext_vector_type(8))) short short8;
typedef __attribute__((ext_vector_type(4))) float f32x4;
typedef unsigned short u16;
typedef unsigned int u32;

// ---------------- workspace layout (bytes) ----------------
#define XB_OFF    0ul            // [512][64][512] bf16 = 33554432
#define WIMG0_OFF 33554432ul     // 128 CUs * 98304 B
#define WIMG1_OFF 46137344ul     // 128 CUs * 131072 B
#define B0_OFF    62914560ul     // 4096 f32
#define B1_OFF    62930944ul     // 4096 f32
#define H0_OFF    62947328ul     // [2][64][1024] bf16 = 262144
#define H1_OFF    63209472ul     // [2][64][1024] bf16 = 262144
#define BAR_OFF   63471616ul     // barrier counter (+pad)
#define ZERO_LEN  524544ul       // H0..BAR inclusive

// ---------------- LDS layout (bytes) ----------------
#define WBYTES_MAX 131072                 // 32 cols * K2 (K2=4096 for layer1)
#define GATES_OFF  WBYTES_MAX             // [64][32] f32 = 8192
#define CST_OFF    (WBYTES_MAX + 8192)    // [64][8]  f32 = 2048
#define BIAS_OFF   (WBYTES_MAX + 8192 + 2048) // [32] f32 = 128
#define LDS_TOTAL  (WBYTES_MAX + 8192 + 2048 + 128)  // 141440 <= 163840

__device__ __forceinline__ u16 f2bf(float f) {
  u32 u = __float_as_uint(f);
  u32 r = (u + 0x7fffu + ((u >> 16) & 1u)) >> 16;   // RNE
  return (u16)r;
}
__device__ __forceinline__ float bf2f(u16 s) { return __uint_as_float(((u32)s) << 16); }

// x[b][t][i] fp32 -> xb[t][b][i] bf16
__global__ __launch_bounds__(256) void prep_x(const float* __restrict__ x,
                                              u16* __restrict__ xb) {
  u32 stride = gridDim.x * blockDim.x;
  for (u32 e = blockIdx.x * blockDim.x + threadIdx.x; e < 16777216u; e += stride) {
    u32 i = e & 511u, b = (e >> 9) & 63u, t = e >> 15;
    xb[e] = f2bf(x[((size_t)b << 18) + ((size_t)t << 9) + i]);
  }
}

// pack per-CU weight LDS images (bf16, col-major rows [col][k], k-bytes XOR-swizzled)
__global__ __launch_bounds__(256) void prep_w(
    const float* __restrict__ wih0, const float* __restrict__ whh0,
    const float* __restrict__ wih1, const float* __restrict__ whh1,
    char* __restrict__ wimg0, char* __restrict__ wimg1) {
  u32 bid = blockIdx.x;            // 8192 rows: cu(0..255) x col n(0..31)
  u32 cu = bid >> 5, n = bid & 31u;
  u32 g = n >> 3, u = n & 7u;
  u32 sw = (n & 15u) << 6;
  if (cu < 128u) {
    u32 grow = g * 1024u + cu * 8u + u;
    char* dst = wimg0 + (size_t)cu * 98304 + (size_t)n * 3072;
    const float* wih = wih0 + (size_t)grow * 512;
    const float* whh = whh0 + (size_t)grow * 1024;
    for (u32 k = threadIdx.x; k < 1536u; k += 256u) {
      float v = (k < 512u) ? wih[k] : whh[k - 512u];
      *(u16*)(dst + ((k * 2u) ^ sw)) = f2bf(v);
    }
  } else {
    u32 lcu = cu - 128u;
    u32 grow = g * 1024u + lcu * 8u + u;
    char* dst = wimg1 + (size_t)lcu * 131072 + (size_t)n * 4096;
    const float* wih = wih1 + (size_t)grow * 1024;
    const float* whh = whh1 + (size_t)grow * 1024;
    for (u32 k = threadIdx.x; k < 2048u; k += 256u) {
      float v = (k < 1024u) ? wih[k] : whh[k - 1024u];
      *(u16*)(dst + ((k * 2u) ^ sw)) = f2bf(v);
    }
  }
}

__global__ __launch_bounds__(256) void prep_b(
    const float* __restrict__ bih0, const float* __restrict__ bhh0,
    const float* __restrict__ bih1, const float* __restrict__ bhh1,
    float* __restrict__ b0s, float* __restrict__ b1s) {
  u32 i = blockIdx.x * 256u + threadIdx.x;
  if (i < 4096u) b0s[i] = bih0[i] + bhh0[i];
  else if (i < 8192u) { u32 j = i - 4096u; b1s[j] = bih1[j] + bhh1[j]; }
}

// Persistent kernel: 256 WGs (1/CU). Blocks 0..127 = layer0 (K=1536: [x_t|h0prev]),
// blocks 128..255 = layer1 (K=2048: [h0cur|h1prev]), pipelined one step behind.
__global__ __launch_bounds__(256, 1) void lstm_persist(
    const u16* __restrict__ xb,
    const u16* __restrict__ wimg0, const u16* __restrict__ wimg1,
    const float* __restrict__ b0s, const float* __restrict__ b1s,
    u16* __restrict__ h0buf, u16* __restrict__ h1buf,
    u32* __restrict__ bar,
    const float* __restrict__ fc_w, const float* __restrict__ fc_b,
    float* __restrict__ out) {
  extern __shared__ char smem[];
  float* gates = (float*)(smem + GATES_OFF);  // [64][32]
  float* cst   = (float*)(smem + CST_OFF);    // [64][8]
  float* bias  = (float*)(smem + BIAS_OFF);   // [32]

  const int cu = blockIdx.x;
  const int layer = cu >> 7;
  const int lcu = cu & 127;
  const int U0 = lcu * 8;
  const int K = layer ? 2048 : 1536;
  const int K2 = K * 2;
  const int tid = threadIdx.x;

  { // one-time: stage this CU's weight image into LDS (linear copy, pre-swizzled)
    const short8* s = layer ? (const short8*)(wimg1 + (size_t)lcu * 65536)
                            : (const short8*)(wimg0 + (size_t)lcu * 49152);
    short8* d = (short8*)smem;
    const int nwords = (32 * K2) / 16;
    for (int i = tid; i < nwords; i += 256) d[i] = s[i];
  }
  if (tid < 32) {
    int grow = (tid >> 3) * 1024 + U0 + (tid & 7);
    bias[tid] = layer ? b1s[grow] : b0s[grow];
  }
  for (int i = tid; i < 512; i += 256) cst[i] = 0.0f;
  __syncthreads();

  const int lane = tid & 63;
  const int wave = tid >> 6;
  const int lr = lane & 15;
  const int lkel = (lane >> 4) * 8;       // element offset within the 32-wide k-tile
  const int nkt = K >> 7;                 // k-tiles per wave: 12 (L0) / 16 (L1)
  const int kw0 = wave * (K >> 2);        // this wave's K-slice start
  const u32 sw = (u32)(lr & 15) << 6;     // (n&15)<<6; n0=lr, n1=lr+16 share it
  const char* wrow0 = smem + (size_t)lr * K2;
  const char* wrow1 = smem + (size_t)(16 + lr) * K2;

  u32 target = 0;
  for (int m = 0; m <= 512; ++m) {
    const bool active = layer ? (m >= 1) : (m < 512);
    if (active) {
      const int t = layer ? (m - 1) : m;
      for (int i = tid; i < 2048; i += 256) gates[i] = 0.0f;
      __syncthreads();

      const u16* srcA; const u16* srcB; int strideA; int KB;
      if (!layer) {
        srcA = xb + (size_t)t * (64 * 512); strideA = 512; KB = 512;
        srcB = h0buf + (size_t)((t & 1) ^ 1) * 65536;          // h0[t-1]
      } else {
        srcA = h0buf + (size_t)(t & 1) * 65536;                // h0[t]
        strideA = 1024; KB = 1024;
        srcB = h1buf + (size_t)((t & 1) ^ 1) * 65536;          // h1[t-1]
      }

      f32x4 z = {0.0f, 0.0f, 0.0f, 0.0f};
      f32x4 acc[4][2];
      #pragma unroll
      for (int a = 0; a < 4; ++a) { acc[a][0] = z; acc[a][1] = z; }

      #pragma unroll 4
      for (int kt = 0; kt < nkt; ++kt) {
        const int k0 = kw0 + (kt << 5);
        const u16* abase; int kk, stride;
        if (k0 < KB) { abase = srcA; kk = k0; stride = strideA; }
        else         { abase = srcB; kk = k0 - KB; stride = 1024; }
        const u16* ap = abase + (size_t)lr * stride + kk + lkel;
        short8 a0 = *(const short8*)(ap);
        short8 a1 = *(const short8*)(ap + 16 * stride);
        short8 a2 = *(const short8*)(ap + 32 * stride);
        short8 a3 = *(const short8*)(ap + 48 * stride);
        const u32 kb = ((u32)(k0 + lkel) * 2u) ^ sw;
        short8 b0 = *(const short8*)(wrow0 + kb);
        short8 b1 = *(const short8*)(wrow1 + kb);
        acc[0][0] = __builtin_amdgcn_mfma_f32_16x16x32_bf16(a0, b0, acc[0][0], 0, 0, 0);
        acc[1][0] = __builtin_amdgcn_mfma_f32_16x16x32_bf16(a1, b0, acc[1][0], 0, 0, 0);
        acc[2][0] = __builtin_amdgcn_mfma_f32_16x16x32_bf16(a2, b0, acc[2][0], 0, 0, 0);
        acc[3][0] = __builtin_amdgcn_mfma_f32_16x16x32_bf16(a3, b0, acc[3][0], 0, 0, 0);
        acc[0][1] = __builtin_amdgcn_mfma_f32_16x16x32_bf16(a0, b1, acc[0][1], 0, 0, 0);
        acc[1][1] = __builtin_amdgcn_mfma_f32_16x16x32_bf16(a1, b1, acc[1][1], 0, 0, 0);
        acc[2][1] = __builtin_amdgcn_mfma_f32_16x16x32_bf16(a2, b1, acc[2][1], 0, 0, 0);
        acc[3][1] = __builtin_amdgcn_mfma_f32_16x16x32_bf16(a3, b1, acc[3][1], 0, 0, 0);
      }

      // K-split reduction across the 4 waves via LDS float atomics
      #pragma unroll
      for (int mt = 0; mt < 4; ++mt)
        #pragma unroll
        for (int nt = 0; nt < 2; ++nt)
          #pragma unroll
          for (int r = 0; r < 4; ++r) {
            int row = mt * 16 + (lane >> 4) * 4 + r;   // batch
            int col = nt * 16 + lr;                    // gate col (local)
            atomicAdd(&gates[row * 32 + col], acc[mt][nt][r]);
          }
      __syncthreads();

      { // nonlinearity + state update: 512 (b,u) pairs over 256 threads
        const int b = tid >> 2;
        const int ub = (tid & 3) * 2;
        u16* hdst = (layer ? h1buf : h0buf) + (size_t)(t & 1) * 65536 + (size_t)b * 1024 + U0;
        #pragma unroll
        for (int du = 0; du < 2; ++du) {
          const int u = ub + du;
          float gi = gates[b * 32 + u]      + bias[u];
          float gf = gates[b * 32 + 8 + u]  + bias[8 + u];
          float gg = gates[b * 32 + 16 + u] + bias[16 + u];
          float go = gates[b * 32 + 24 + u] + bias[24 + u];
          float ii = 1.0f / (1.0f + __expf(-gi));
          float ff = 1.0f / (1.0f + __expf(-gf));
          float g2 = 1.0f - 2.0f / (__expf(2.0f * gg) + 1.0f);
          float oo = 1.0f / (1.0f + __expf(-go));
          float c = ff * cst[b * 8 + u] + ii * g2;
          cst[b * 8 + u] = c;
          float h = oo * (1.0f - 2.0f / (__expf(2.0f * c) + 1.0f));
          hdst[u] = f2bf(h);
        }
      }
    }
    // ---- grid barrier (monotonic counter, device-scope) ----
    __syncthreads();
    target += 256u;
    if (tid == 0) {
      __threadfence();                       // release (L2 wb)
      atomicAdd(bar, 1u);
      while (__hip_atomic_load(bar, __ATOMIC_RELAXED, __HIP_MEMORY_SCOPE_AGENT) < target) {
        __builtin_amdgcn_s_sleep(1);
      }
      __threadfence();                       // acquire (inv)
    }
    __syncthreads();
  }

  // FC + softmax epilogue on block 0 (h1[511] lives in buffer 1)
  if (cu == 0 && tid < 128) {
    const int b = tid >> 1, cls = tid & 1;
    const u16* hrow = h1buf + 65536 + (size_t)b * 1024;
    const float* w = fc_w + (size_t)cls * 1024;
    float sum = fc_b[cls];
    for (int j = 0; j < 1024; j += 8) {
      short8 hv = *(const short8*)(hrow + j);
      #pragma unroll
      for (int e = 0; e < 8; ++e) sum += bf2f((u16)hv[e]) * w[j + e];
    }
    float other = __shfl_xor(sum, 1);
    float mx = fmaxf(sum, other);
    float e0 = __expf(sum - mx), e1 = __expf(other - mx);
    out[b * 2 + cls] = e0 / (e0 + e1);
  }
}

extern "C" void kernel_launch(void* const* d_in, const int* in_sizes, int n_in,
                              void* d_out, int out_size, void* d_ws, size_t ws_size,
                              hipStream_t stream) {
  const float* x    = (const float*)d_in[0];
  const float* wih0 = (const float*)d_in[1];
  const float* whh0 = (const float*)d_in[2];
  const float* bih0 = (const float*)d_in[3];
  const float* bhh0 = (const float*)d_in[4];
  const float* wih1 = (const float*)d_in[5];
  const float* whh1 = (const float*)d_in[6];
  const float* bih1 = (const float*)d_in[7];
  const float* bhh1 = (const float*)d_in[8];
  const float* fcw  = (const float*)d_in[9];
  const float* fcb  = (const float*)d_in[10];
  float* out = (float*)d_out;
  char* ws = (char*)d_ws;

  u16* xb     = (u16*)(ws + XB_OFF);
  char* wimg0 = ws + WIMG0_OFF;
  char* wimg1 = ws + WIMG1_OFF;
  float* b0s  = (float*)(ws + B0_OFF);
  float* b1s  = (float*)(ws + B1_OFF);
  u16* h0buf  = (u16*)(ws + H0_OFF);
  u16* h1buf  = (u16*)(ws + H1_OFF);
  u32* bar    = (u32*)(ws + BAR_OFF);

  (void)hipFuncSetAttribute((const void*)lstm_persist,
      hipFuncAttributeMaxDynamicSharedMemorySize, LDS_TOTAL);

  hipMemsetAsync(ws + H0_OFF, 0, ZERO_LEN, stream);   // zero h buffers + barrier
  prep_x<<<8192, 256, 0, stream>>>(x, xb);
  prep_w<<<8192, 256, 0, stream>>>(wih0, whh0, wih1, whh1, wimg0, wimg1);
  prep_b<<<32, 256, 0, stream>>>(bih0, bhh0, bih1, bhh1, b0s, b1s);
  lstm_persist<<<256, 256, LDS_TOTAL, stream>>>(
      (const u16*)xb, (const u16*)wimg0, (const u16*)wimg1, b0s, b1s,
      h0buf, h1buf, bar, fcw, fcb, out);
}

// Round 2
// 10688.810 us; speedup vs baseline: 1.8428x; 1.8428x over previous
//
#include <hip/hip_runtime.h>

typedef __attribute__((ext_vector_type(8))) short short8;
typedef __attribute__((ext_vector_type(4))) float f32x4;
typedef unsigned short u16;
typedef unsigned int u32;

// ---------------- workspace layout (bytes) ----------------
// xb:  [512][64][512] bf16                      = 33,554,432
// h0h: [513][64][1024] bf16 (slot t+1 = h0[t])  = 67,239,936
// h1h: [513][64][1024] bf16                     = 67,239,936
// f0:  [513][128] u32 flags                     =    262,656
// f1:  [513][128] u32 flags                     =    262,656
// total ~160.8 MB
#define XB_OFF 0ul
#define H0_OFF 33554432ul
#define H1_OFF 100794368ul
#define F0_OFF 168034304ul
#define F1_OFF 168296960ul
#define FLAGS_LEN 525312ul

// ---------------- LDS layout (bytes) ----------------
#define WB_MAX    131072                  // 32 cols * 2*K bytes (K=2048 for L1)
#define GATES_OFF WB_MAX                  // [64][32] f32 = 8192
#define CST_OFF   (WB_MAX + 8192)         // [64][8]  f32 = 2048
#define BIAS_OFF  (WB_MAX + 8192 + 2048)  // [32] f32 = 128
#define LDS_TOTAL (WB_MAX + 8192 + 2048 + 128)   // 141440 <= 163840

__device__ __forceinline__ u16 f2bf(float f) {
  u32 u = __float_as_uint(f);
  return (u16)((u + 0x7fffu + ((u >> 16) & 1u)) >> 16);   // RNE
}
__device__ __forceinline__ float bf2f(u16 s) { return __uint_as_float(((u32)s) << 16); }

// x[b][t][i] fp32 -> xb[t][b][i] bf16
__global__ __launch_bounds__(256) void prep_x(const float* __restrict__ x,
                                              u16* __restrict__ xb) {
  u32 stride = gridDim.x * blockDim.x;
  for (u32 e = blockIdx.x * blockDim.x + threadIdx.x; e < 16777216u; e += stride) {
    u32 i = e & 511u, b = (e >> 9) & 63u, t = e >> 15;
    xb[e] = f2bf(x[((size_t)b << 18) + ((size_t)t << 9) + i]);
  }
}

// Persistent kernel, 256 blocks (1/CU). Blocks 0..127: layer0 (K=1536 = [x|h0prev]).
// Blocks 128..255: layer1 (K=2048 = [h0cur|h1prev]). No grid barrier: per-CU
// ready-flags at the coherence point; h history never reuses addresses.
__global__ __launch_bounds__(256, 1) void lstm_persist(
    const u16* __restrict__ xb,
    const float* __restrict__ wih0, const float* __restrict__ whh0,
    const float* __restrict__ bih0, const float* __restrict__ bhh0,
    const float* __restrict__ wih1, const float* __restrict__ whh1,
    const float* __restrict__ bih1, const float* __restrict__ bhh1,
    u16* __restrict__ h0h, u16* __restrict__ h1h,
    u32* __restrict__ f0, u32* __restrict__ f1,
    const float* __restrict__ fc_w, const float* __restrict__ fc_b,
    float* __restrict__ out) {
  extern __shared__ char smem[];
  float* gates = (float*)(smem + GATES_OFF);  // [64][32]
  float* cst   = (float*)(smem + CST_OFF);    // [64][8]
  float* bias  = (float*)(smem + BIAS_OFF);   // [32]

  const int cu = blockIdx.x;
  const int layer = cu >> 7;
  const int lcu = cu & 127;
  const int U0 = lcu * 8;
  const int K2 = layer ? 4096 : 3072;         // bytes per LDS weight column
  const int tid = threadIdx.x;

  // ---- startup: pack this CU's 32 weight columns (bf16, k-byte XOR swizzle) ----
  for (int n = 0; n < 32; ++n) {
    const int grow = (n >> 3) * 1024 + U0 + (n & 7);
    char* colbase = smem + n * K2;
    const u32 swn = (u32)(n & 15) << 6;
    if (!layer) {
      const float* rih = wih0 + (size_t)grow * 512;
      const float* rhh = whh0 + (size_t)grow * 1024;
      for (int k = tid; k < 1536; k += 256) {
        float v = (k < 512) ? rih[k] : rhh[k - 512];
        *(u16*)(colbase + (((u32)k * 2u) ^ swn)) = f2bf(v);
      }
    } else {
      const float* rih = wih1 + (size_t)grow * 1024;
      const float* rhh = whh1 + (size_t)grow * 1024;
      for (int k = tid; k < 2048; k += 256) {
        float v = (k < 1024) ? rih[k] : rhh[k - 1024];
        *(u16*)(colbase + (((u32)k * 2u) ^ swn)) = f2bf(v);
      }
    }
  }
  if (tid < 32) {
    int grow = (tid >> 3) * 1024 + U0 + (tid & 7);
    bias[tid] = layer ? (bih1[grow] + bhh1[grow]) : (bih0[grow] + bhh0[grow]);
  }
  for (int i = tid; i < 512; i += 256) cst[i] = 0.0f;
  __syncthreads();

  const int lane = tid & 63;
  const int wave = tid >> 6;
  const int lr = lane & 15;
  const int lkel = (lane >> 4) * 8;
  const u32 sw = (u32)lr << 6;
  const char* wrow0 = smem + (size_t)lr * K2;
  const char* wrow1 = smem + (size_t)(16 + lr) * K2;

  // spin until all 128 flags at `base` are set (wave 0 only; caller syncs)
  auto poll = [&](const u32* base) {
    if (wave == 0) {
      #pragma unroll
      for (int j = 0; j < 2; ++j) {
        const u32* p = base + lane + j * 64;
        while (__hip_atomic_load(p, __ATOMIC_RELAXED, __HIP_MEMORY_SCOPE_AGENT) == 0u)
          __builtin_amdgcn_s_sleep(2);
      }
    }
  };

  for (int t = 0; t < 512; ++t) {
    for (int i = tid; i < 2048; i += 256) gates[i] = 0.0f;

    f32x4 z = {0.0f, 0.0f, 0.0f, 0.0f};
    f32x4 acc[4][2];
    #pragma unroll
    for (int a = 0; a < 4; ++a) { acc[a][0] = z; acc[a][1] = z; }

    // one 64x32x32 k-tile: A rows from `ap` (stride elems), B cols from LDS at k0
    auto do_tile = [&](const u16* Abase, int strideA, int kk, int k0) {
      const u16* ap = Abase + (size_t)lr * strideA + kk + lkel;
      short8 a0 = *(const short8*)(ap);
      short8 a1 = *(const short8*)(ap + 16 * strideA);
      short8 a2 = *(const short8*)(ap + 32 * strideA);
      short8 a3 = *(const short8*)(ap + 48 * strideA);
      const u32 kb = ((u32)(k0 + lkel) * 2u) ^ sw;
      short8 b0 = *(const short8*)(wrow0 + kb);
      short8 b1 = *(const short8*)(wrow1 + kb);
      acc[0][0] = __builtin_amdgcn_mfma_f32_16x16x32_bf16(a0, b0, acc[0][0], 0, 0, 0);
      acc[1][0] = __builtin_amdgcn_mfma_f32_16x16x32_bf16(a1, b0, acc[1][0], 0, 0, 0);
      acc[2][0] = __builtin_amdgcn_mfma_f32_16x16x32_bf16(a2, b0, acc[2][0], 0, 0, 0);
      acc[3][0] = __builtin_amdgcn_mfma_f32_16x16x32_bf16(a3, b0, acc[3][0], 0, 0, 0);
      acc[0][1] = __builtin_amdgcn_mfma_f32_16x16x32_bf16(a0, b1, acc[0][1], 0, 0, 0);
      acc[1][1] = __builtin_amdgcn_mfma_f32_16x16x32_bf16(a1, b1, acc[1][1], 0, 0, 0);
      acc[2][1] = __builtin_amdgcn_mfma_f32_16x16x32_bf16(a2, b1, acc[2][1], 0, 0, 0);
      acc[3][1] = __builtin_amdgcn_mfma_f32_16x16x32_bf16(a3, b1, acc[3][1], 0, 0, 0);
    };

    if (!layer) {
      // phase A: x-part (independent of flags) — hides the h0[t-1] wait
      const u16* Ax = xb + (size_t)t * 32768;
      #pragma unroll
      for (int j = 0; j < 4; ++j) {
        int k0 = (wave + 4 * j) * 32;
        do_tile(Ax, 512, k0, k0);
      }
      if (t > 0) poll(f0 + (size_t)t * 128);
      __syncthreads();
      if (t > 0) {
        const u16* Ah = h0h + (size_t)t * 65536;     // h0[t-1]
        #pragma unroll
        for (int j = 4; j < 12; ++j) {
          int k0 = (wave + 4 * j) * 32;
          do_tile(Ah, 1024, k0 - 512, k0);
        }
      }
    } else {
      // phase A: h1[t-1]-part (own-layer recurrence, flags usually long set)
      if (t > 0) poll(f1 + (size_t)t * 128);
      __syncthreads();
      if (t > 0) {
        const u16* Ah1 = h1h + (size_t)t * 65536;    // h1[t-1]
        #pragma unroll
        for (int j = 8; j < 16; ++j) {
          int k0 = (wave + 4 * j) * 32;
          do_tile(Ah1, 1024, k0 - 1024, k0);
        }
      }
      // phase B: h0[t]-part (the fresh dependency)
      poll(f0 + (size_t)(t + 1) * 128);
      __syncthreads();
      const u16* Ah0 = h0h + (size_t)(t + 1) * 65536; // h0[t]
      #pragma unroll
      for (int j = 0; j < 8; ++j) {
        int k0 = (wave + 4 * j) * 32;
        do_tile(Ah0, 1024, k0, k0);
      }
    }

    // K-split reduction across 4 waves via LDS float atomics
    #pragma unroll
    for (int mt = 0; mt < 4; ++mt)
      #pragma unroll
      for (int nt = 0; nt < 2; ++nt)
        #pragma unroll
        for (int r = 0; r < 4; ++r) {
          int row = mt * 16 + (lane >> 4) * 4 + r;   // batch
          int col = nt * 16 + lr;                    // local gate col
          atomicAdd(&gates[row * 32 + col], acc[mt][nt][r]);
        }
    __syncthreads();

    { // nonlinearity + state update; h stored sc1 (agent) into fresh history slot
      const int b = tid >> 2;
      const int ub = (tid & 3) * 2;
      float hv[2];
      #pragma unroll
      for (int du = 0; du < 2; ++du) {
        const int u = ub + du;
        float gi = gates[b * 32 + u]      + bias[u];
        float gf = gates[b * 32 + 8 + u]  + bias[8 + u];
        float gg = gates[b * 32 + 16 + u] + bias[16 + u];
        float go = gates[b * 32 + 24 + u] + bias[24 + u];
        float ii = 1.0f / (1.0f + __expf(-gi));
        float ff = 1.0f / (1.0f + __expf(-gf));
        float g2 = 1.0f - 2.0f / (__expf(2.0f * gg) + 1.0f);
        float oo = 1.0f / (1.0f + __expf(-go));
        float c = ff * cst[b * 8 + u] + ii * g2;
        cst[b * 8 + u] = c;
        hv[du] = oo * (1.0f - 2.0f / (__expf(2.0f * c) + 1.0f));
      }
      u32 packed = (u32)f2bf(hv[0]) | ((u32)f2bf(hv[1]) << 16);
      u16* hist = layer ? h1h : h0h;
      u32* dst = (u32*)(hist + (size_t)(t + 1) * 65536 + (size_t)b * 1024 + U0 + ub);
      __hip_atomic_store(dst, packed, __ATOMIC_RELAXED, __HIP_MEMORY_SCOPE_AGENT);
    }
    __syncthreads();   // compiler drains vmcnt(0) per wave before s_barrier
    if (tid == 0) {
      asm volatile("s_waitcnt vmcnt(0)" ::: "memory");
      u32* fl = (layer ? f1 : f0) + (size_t)(t + 1) * 128 + lcu;
      __hip_atomic_store(fl, 1u, __ATOMIC_RELAXED, __HIP_MEMORY_SCOPE_AGENT);
    }
  }

  // FC + softmax epilogue on block 0 (reads h1[511] = slot 512)
  if (cu == 0) {
    poll(f1 + (size_t)512 * 128);
    __syncthreads();
    if (tid < 128) {
      const int b = tid >> 1, cls = tid & 1;
      const u16* hrow = h1h + (size_t)512 * 65536 + (size_t)b * 1024;
      const float* w = fc_w + (size_t)cls * 1024;
      float sum = fc_b[cls];
      for (int j = 0; j < 1024; j += 8) {
        short8 hvv = *(const short8*)(hrow + j);
        #pragma unroll
        for (int e = 0; e < 8; ++e) sum += bf2f((u16)hvv[e]) * w[j + e];
      }
      float other = __shfl_xor(sum, 1);
      float mx = fmaxf(sum, other);
      float e0 = __expf(sum - mx), e1 = __expf(other - mx);
      out[b * 2 + cls] = e0 / (e0 + e1);
    }
  }
}

extern "C" void kernel_launch(void* const* d_in, const int* in_sizes, int n_in,
                              void* d_out, int out_size, void* d_ws, size_t ws_size,
                              hipStream_t stream) {
  const float* x    = (const float*)d_in[0];
  const float* wih0 = (const float*)d_in[1];
  const float* whh0 = (const float*)d_in[2];
  const float* bih0 = (const float*)d_in[3];
  const float* bhh0 = (const float*)d_in[4];
  const float* wih1 = (const float*)d_in[5];
  const float* whh1 = (const float*)d_in[6];
  const float* bih1 = (const float*)d_in[7];
  const float* bhh1 = (const float*)d_in[8];
  const float* fcw  = (const float*)d_in[9];
  const float* fcb  = (const float*)d_in[10];
  float* out = (float*)d_out;
  char* ws = (char*)d_ws;

  u16* xb    = (u16*)(ws + XB_OFF);
  u16* h0h   = (u16*)(ws + H0_OFF);
  u16* h1h   = (u16*)(ws + H1_OFF);
  u32* f0    = (u32*)(ws + F0_OFF);
  u32* f1    = (u32*)(ws + F1_OFF);

  (void)hipFuncSetAttribute((const void*)lstm_persist,
      hipFuncAttributeMaxDynamicSharedMemorySize, LDS_TOTAL);

  hipMemsetAsync(ws + F0_OFF, 0, FLAGS_LEN, stream);   // zero ready-flags
  prep_x<<<8192, 256, 0, stream>>>(x, xb);
  lstm_persist<<<256, 256, LDS_TOTAL, stream>>>(
      (const u16*)xb, wih0, whh0, bih0, bhh0, wih1, whh1, bih1, bhh1,
      h0h, h1h, f0, f1, fcw, fcb, out);
}

// Round 3
// 10602.101 us; speedup vs baseline: 1.8579x; 1.0082x over previous
//
#include <hip/hip_runtime.h>

typedef __attribute__((ext_vector_type(8))) short short8;
typedef __attribute__((ext_vector_type(4))) float f32x4;
typedef unsigned short u16;
typedef unsigned int u32;

// ---------------- workspace layout (bytes) ----------------
// xb:  [512][64][512] bf16                      = 33,554,432
// h0h: [513][64][1024] bf16 (slot t+1 = h0[t])  = 67,239,936
// h1h: [513][64][1024] bf16                     = 67,239,936
// f0:  [128] monotonic step flags, 128B apart   =     16,384
// f1:  [128] monotonic step flags, 128B apart   =     16,384
#define XB_OFF 0ul
#define H0_OFF 33554432ul
#define H1_OFF 100794368ul
#define F0_OFF 168034304ul
#define F1_OFF 168050688ul
#define FLAGS_LEN 32768ul

// ---------------- LDS layout (bytes) ----------------
#define WB_MAX    131072                  // 32 cols * 2*K bytes (K=2048 for L1)
#define GATES_OFF WB_MAX                  // [64][32] f32 = 8192
#define CST_OFF   (WB_MAX + 8192)         // [64][8]  f32 = 2048
#define BIAS_OFF  (WB_MAX + 8192 + 2048)  // [32] f32 = 128
#define LDS_TOTAL (WB_MAX + 8192 + 2048 + 128)   // 141440 <= 163840

__device__ __forceinline__ u16 f2bf(float f) {
  u32 u = __float_as_uint(f);
  return (u16)((u + 0x7fffu + ((u >> 16) & 1u)) >> 16);   // RNE
}
__device__ __forceinline__ float bf2f(u16 s) { return __uint_as_float(((u32)s) << 16); }

// exactly one device-scope (IC) load, no cache maintenance
__device__ __forceinline__ u32 load_sc01(const u32* p) {
  u32 v;
  asm volatile("global_load_dword %0, %1, off sc0 sc1\n\ts_waitcnt vmcnt(0)"
               : "=v"(v) : "v"(p) : "memory");
  return v;
}
// exactly one device-scope (IC) store
__device__ __forceinline__ void store_sc01(u32* p, u32 v) {
  asm volatile("global_store_dword %0, %1, off sc0 sc1" :: "v"(p), "v"(v) : "memory");
}

// x[b][t][i] fp32 -> xb[t][b][i] bf16
__global__ __launch_bounds__(256) void prep_x(const float* __restrict__ x,
                                              u16* __restrict__ xb) {
  u32 stride = gridDim.x * blockDim.x;
  for (u32 e = blockIdx.x * blockDim.x + threadIdx.x; e < 16777216u; e += stride) {
    u32 i = e & 511u, b = (e >> 9) & 63u, t = e >> 15;
    xb[e] = f2bf(x[((size_t)b << 18) + ((size_t)t << 9) + i]);
  }
}

// Persistent kernel, 256 blocks (1/CU). Blocks 0..127: layer0 (K=1536 = [x|h0prev]).
// Blocks 128..255: layer1 (K=2048 = [h0cur|h1prev]). Sync: per-CU monotonic step
// flags (own cache line each) at the coherence point; h history never reuses
// addresses, so consumers use normal cached loads.
__global__ __launch_bounds__(256, 1) void lstm_persist(
    const u16* __restrict__ xb,
    const float* __restrict__ wih0, const float* __restrict__ whh0,
    const float* __restrict__ bih0, const float* __restrict__ bhh0,
    const float* __restrict__ wih1, const float* __restrict__ whh1,
    const float* __restrict__ bih1, const float* __restrict__ bhh1,
    u16* __restrict__ h0h, u16* __restrict__ h1h,
    u32* __restrict__ f0, u32* __restrict__ f1,
    const float* __restrict__ fc_w, const float* __restrict__ fc_b,
    float* __restrict__ out) {
  extern __shared__ char smem[];
  float* gates = (float*)(smem + GATES_OFF);  // [64][32]
  float* cst   = (float*)(smem + CST_OFF);    // [64][8]
  float* bias  = (float*)(smem + BIAS_OFF);   // [32]

  const int cu = blockIdx.x;
  const int layer = cu >> 7;
  const int lcu = cu & 127;
  const int U0 = lcu * 8;
  const int K2 = layer ? 4096 : 3072;         // bytes per LDS weight column
  const int tid = threadIdx.x;

  // ---- startup: pack this CU's 32 weight columns (bf16, k-byte XOR swizzle) ----
  for (int n = 0; n < 32; ++n) {
    const int grow = (n >> 3) * 1024 + U0 + (n & 7);
    char* colbase = smem + n * K2;
    const u32 swn = (u32)(n & 15) << 6;
    if (!layer) {
      const float* rih = wih0 + (size_t)grow * 512;
      const float* rhh = whh0 + (size_t)grow * 1024;
      for (int k = tid; k < 1536; k += 256) {
        float v = (k < 512) ? rih[k] : rhh[k - 512];
        *(u16*)(colbase + (((u32)k * 2u) ^ swn)) = f2bf(v);
      }
    } else {
      const float* rih = wih1 + (size_t)grow * 1024;
      const float* rhh = whh1 + (size_t)grow * 1024;
      for (int k = tid; k < 2048; k += 256) {
        float v = (k < 1024) ? rih[k] : rhh[k - 1024];
        *(u16*)(colbase + (((u32)k * 2u) ^ swn)) = f2bf(v);
      }
    }
  }
  if (tid < 32) {
    int grow = (tid >> 3) * 1024 + U0 + (tid & 7);
    bias[tid] = layer ? (bih1[grow] + bhh1[grow]) : (bih0[grow] + bhh0[grow]);
  }
  for (int i = tid; i < 512; i += 256) cst[i] = 0.0f;
  __syncthreads();

  const int lane = tid & 63;
  const int wave = tid >> 6;
  const int lr = lane & 15;
  const int lkel = (lane >> 4) * 8;
  const u32 sw = (u32)lr << 6;
  const char* wrow0 = smem + (size_t)lr * K2;
  const char* wrow1 = smem + (size_t)(16 + lr) * K2;

  // wave 0: wait until every producer flag >= target (each flag on own line)
  auto poll = [&](const u32* base, u32 target) {
    if (wave == 0) {
      #pragma unroll
      for (int j = 0; j < 2; ++j) {
        const u32* p = base + (u32)(lane + 64 * j) * 32u;
        while (load_sc01(p) < target) __builtin_amdgcn_s_sleep(4);
      }
    }
  };

  for (int t = 0; t < 512; ++t) {
    for (int i = tid; i < 2048; i += 256) gates[i] = 0.0f;

    f32x4 z = {0.0f, 0.0f, 0.0f, 0.0f};
    f32x4 acc[4][2];
    #pragma unroll
    for (int a = 0; a < 4; ++a) { acc[a][0] = z; acc[a][1] = z; }

    // one 64x32x32 k-tile: A rows from global (stride elems), B cols from LDS at k0
    auto do_tile = [&](const u16* Abase, int strideA, int kk, int k0) {
      const u16* ap = Abase + (size_t)lr * strideA + kk + lkel;
      short8 a0 = *(const short8*)(ap);
      short8 a1 = *(const short8*)(ap + 16 * strideA);
      short8 a2 = *(const short8*)(ap + 32 * strideA);
      short8 a3 = *(const short8*)(ap + 48 * strideA);
      const u32 kb = ((u32)(k0 + lkel) * 2u) ^ sw;
      short8 b0 = *(const short8*)(wrow0 + kb);
      short8 b1 = *(const short8*)(wrow1 + kb);
      acc[0][0] = __builtin_amdgcn_mfma_f32_16x16x32_bf16(a0, b0, acc[0][0], 0, 0, 0);
      acc[1][0] = __builtin_amdgcn_mfma_f32_16x16x32_bf16(a1, b0, acc[1][0], 0, 0, 0);
      acc[2][0] = __builtin_amdgcn_mfma_f32_16x16x32_bf16(a2, b0, acc[2][0], 0, 0, 0);
      acc[3][0] = __builtin_amdgcn_mfma_f32_16x16x32_bf16(a3, b0, acc[3][0], 0, 0, 0);
      acc[0][1] = __builtin_amdgcn_mfma_f32_16x16x32_bf16(a0, b1, acc[0][1], 0, 0, 0);
      acc[1][1] = __builtin_amdgcn_mfma_f32_16x16x32_bf16(a1, b1, acc[1][1], 0, 0, 0);
      acc[2][1] = __builtin_amdgcn_mfma_f32_16x16x32_bf16(a2, b1, acc[2][1], 0, 0, 0);
      acc[3][1] = __builtin_amdgcn_mfma_f32_16x16x32_bf16(a3, b1, acc[3][1], 0, 0, 0);
    };

    if (!layer) {
      // phase A: x-part (flag-independent) — overlaps the producers' tail
      const u16* Ax = xb + (size_t)t * 32768;
      #pragma unroll
      for (int j = 0; j < 4; ++j) {
        int k0 = (wave + 4 * j) * 32;
        do_tile(Ax, 512, k0, k0);
      }
      if (t > 0) poll(f0, (u32)t);
      __syncthreads();
      if (t > 0) {
        const u16* Ah = h0h + (size_t)t * 65536;     // h0[t-1]
        #pragma unroll
        for (int j = 4; j < 12; ++j) {
          int k0 = (wave + 4 * j) * 32;
          do_tile(Ah, 1024, k0 - 512, k0);
        }
      }
    } else {
      // phase A: h1[t-1]-part (own-layer recurrence)
      if (t > 0) poll(f1, (u32)t);
      __syncthreads();
      if (t > 0) {
        const u16* Ah1 = h1h + (size_t)t * 65536;    // h1[t-1]
        #pragma unroll
        for (int j = 8; j < 16; ++j) {
          int k0 = (wave + 4 * j) * 32;
          do_tile(Ah1, 1024, k0 - 1024, k0);
        }
      }
      // phase B: h0[t]-part (the fresh dependency)
      poll(f0, (u32)(t + 1));
      __syncthreads();
      const u16* Ah0 = h0h + (size_t)(t + 1) * 65536; // h0[t]
      #pragma unroll
      for (int j = 0; j < 8; ++j) {
        int k0 = (wave + 4 * j) * 32;
        do_tile(Ah0, 1024, k0, k0);
      }
    }

    // K-split reduction across 4 waves via LDS float atomics
    #pragma unroll
    for (int mt = 0; mt < 4; ++mt)
      #pragma unroll
      for (int nt = 0; nt < 2; ++nt)
        #pragma unroll
        for (int r = 0; r < 4; ++r) {
          int row = mt * 16 + (lane >> 4) * 4 + r;   // batch
          int col = nt * 16 + lr;                    // local gate col
          atomicAdd(&gates[row * 32 + col], acc[mt][nt][r]);
        }
    __syncthreads();

    { // nonlinearity + state update; h stored sc0sc1 into fresh history slot
      const int b = tid >> 2;
      const int ub = (tid & 3) * 2;
      float hv[2];
      #pragma unroll
      for (int du = 0; du < 2; ++du) {
        const int u = ub + du;
        float gi = gates[b * 32 + u]      + bias[u];
        float gf = gates[b * 32 + 8 + u]  + bias[8 + u];
        float gg = gates[b * 32 + 16 + u] + bias[16 + u];
        float go = gates[b * 32 + 24 + u] + bias[24 + u];
        float ii = 1.0f / (1.0f + __expf(-gi));
        float ff = 1.0f / (1.0f + __expf(-gf));
        float g2 = 1.0f - 2.0f / (__expf(2.0f * gg) + 1.0f);
        float oo = 1.0f / (1.0f + __expf(-go));
        float c = ff * cst[b * 8 + u] + ii * g2;
        cst[b * 8 + u] = c;
        hv[du] = oo * (1.0f - 2.0f / (__expf(2.0f * c) + 1.0f));
      }
      u32 packed = (u32)f2bf(hv[0]) | ((u32)f2bf(hv[1]) << 16);
      u16* hist = layer ? h1h : h0h;
      u32* dst = (u32*)(hist + (size_t)(t + 1) * 65536 + (size_t)b * 1024 + U0 + ub);
      store_sc01(dst, packed);
    }
    asm volatile("s_waitcnt vmcnt(0)" ::: "memory");  // h slice ack'd at IC
    __syncthreads();                                  // all waves drained
    if (tid == 0) {
      u32* fl = (layer ? f1 : f0) + (u32)lcu * 32u;
      store_sc01(fl, (u32)(t + 1));                   // publish step t done
    }
  }

  // FC + softmax epilogue on block 0 (reads h1[511] = slot 512)
  if (cu == 0) {
    poll(f1, 512u);
    __syncthreads();
    if (tid < 128) {
      const int b = tid >> 1, cls = tid & 1;
      const u16* hrow = h1h + (size_t)512 * 65536 + (size_t)b * 1024;
      const float* w = fc_w + (size_t)cls * 1024;
      float sum = fc_b[cls];
      for (int j = 0; j < 1024; j += 8) {
        short8 hvv = *(const short8*)(hrow + j);
        #pragma unroll
        for (int e = 0; e < 8; ++e) sum += bf2f((u16)hvv[e]) * w[j + e];
      }
      float other = __shfl_xor(sum, 1);
      float mx = fmaxf(sum, other);
      float e0 = __expf(sum - mx), e1 = __expf(other - mx);
      out[b * 2 + cls] = e0 / (e0 + e1);
    }
  }
}

extern "C" void kernel_launch(void* const* d_in, const int* in_sizes, int n_in,
                              void* d_out, int out_size, void* d_ws, size_t ws_size,
                              hipStream_t stream) {
  const float* x    = (const float*)d_in[0];
  const float* wih0 = (const float*)d_in[1];
  const float* whh0 = (const float*)d_in[2];
  const float* bih0 = (const float*)d_in[3];
  const float* bhh0 = (const float*)d_in[4];
  const float* wih1 = (const float*)d_in[5];
  const float* whh1 = (const float*)d_in[6];
  const float* bih1 = (const float*)d_in[7];
  const float* bhh1 = (const float*)d_in[8];
  const float* fcw  = (const float*)d_in[9];
  const float* fcb  = (const float*)d_in[10];
  float* out = (float*)d_out;
  char* ws = (char*)d_ws;

  u16* xb    = (u16*)(ws + XB_OFF);
  u16* h0h   = (u16*)(ws + H0_OFF);
  u16* h1h   = (u16*)(ws + H1_OFF);
  u32* f0    = (u32*)(ws + F0_OFF);
  u32* f1    = (u32*)(ws + F1_OFF);

  (void)hipFuncSetAttribute((const void*)lstm_persist,
      hipFuncAttributeMaxDynamicSharedMemorySize, LDS_TOTAL);

  hipMemsetAsync(ws + F0_OFF, 0, FLAGS_LEN, stream);   // zero step flags
  prep_x<<<8192, 256, 0, stream>>>(x, xb);
  lstm_persist<<<256, 256, LDS_TOTAL, stream>>>(
      (const u16*)xb, wih0, whh0, bih0, bhh0, wih1, whh1, bih1, bhh1,
      h0h, h1h, f0, f1, fcw, fcb, out);
}

// Round 4
// 8556.982 us; speedup vs baseline: 2.3019x; 1.2390x over previous
//
#include <hip/hip_runtime.h>

typedef __attribute__((ext_vector_type(8))) short short8;
typedef __attribute__((ext_vector_type(4))) float f32x4;
typedef unsigned short u16;
typedef unsigned int u32;

// ---------------- workspace layout (bytes) ----------------
// xb:  [512][64][512] bf16                          = 33,554,432
// h0h: [513][128 cu][64 b][8 u] bf16 (slot t+1=h[t])= 67,239,936
// h1h: same                                          = 67,239,936
// f0/f1: [128] monotonic step flags, 128B apart      = 16,384 each
#define XB_OFF 0ul
#define H0_OFF 33554432ul
#define H1_OFF 100794368ul
#define F0_OFF 168034304ul
#define F1_OFF 168050688ul
#define FLAGS_LEN 32768ul

// ---------------- LDS layout (bytes) ----------------
#define WB_MAX    131072                  // 32 cols * 2*K bytes (K=2048 for L1)
#define GATES_OFF WB_MAX                  // [64][32] f32 = 8192
#define CST_OFF   (WB_MAX + 8192)         // [64][8]  f32 = 2048
#define BIAS_OFF  (WB_MAX + 8192 + 2048)  // [32] f32 = 128
#define LDS_TOTAL (WB_MAX + 8192 + 2048 + 128)   // 141440 <= 163840

__device__ __forceinline__ u16 f2bf(float f) {
  u32 u = __float_as_uint(f);
  return (u16)((u + 0x7fffu + ((u >> 16) & 1u)) >> 16);   // RNE
}
__device__ __forceinline__ float bf2f(u16 s) { return __uint_as_float(((u32)s) << 16); }

__device__ __forceinline__ u32 load_sc01(const u32* p) {
  u32 v;
  asm volatile("global_load_dword %0, %1, off sc0 sc1\n\ts_waitcnt vmcnt(0)"
               : "=v"(v) : "v"(p) : "memory");
  return v;
}
__device__ __forceinline__ void store_sc01(u32* p, u32 v) {
  asm volatile("global_store_dword %0, %1, off sc0 sc1" :: "v"(p), "v"(v) : "memory");
}

// x[b][t][i] fp32 -> xb[t][b][i] bf16
__global__ __launch_bounds__(256) void prep_x(const float* __restrict__ x,
                                              u16* __restrict__ xb) {
  u32 stride = gridDim.x * blockDim.x;
  for (u32 e = blockIdx.x * blockDim.x + threadIdx.x; e < 16777216u; e += stride) {
    u32 i = e & 511u, b = (e >> 9) & 63u, t = e >> 15;
    xb[e] = f2bf(x[((size_t)b << 18) + ((size_t)t << 9) + i]);
  }
}

// Persistent kernel, 256 blocks (1/CU). Blocks 0..127: layer0 (K=1536 = [x|h0prev]).
// Blocks 128..255: layer1 (K=2048 = [h0cur|h1prev]).
// h history layout [t][cu][b][u]: producer stores are 1KB fully-coalesced; each
// consumer wave polls only the 32 producer flags covering its K-slice (no barrier).
__global__ __launch_bounds__(256, 1) void lstm_persist(
    const u16* __restrict__ xb,
    const float* __restrict__ wih0, const float* __restrict__ whh0,
    const float* __restrict__ bih0, const float* __restrict__ bhh0,
    const float* __restrict__ wih1, const float* __restrict__ whh1,
    const float* __restrict__ bih1, const float* __restrict__ bhh1,
    u16* __restrict__ h0h, u16* __restrict__ h1h,
    u32* __restrict__ f0, u32* __restrict__ f1,
    const float* __restrict__ fc_w, const float* __restrict__ fc_b,
    float* __restrict__ out) {
  extern __shared__ char smem[];
  float* gates = (float*)(smem + GATES_OFF);  // [64][32]
  float* cst   = (float*)(smem + CST_OFF);    // [64][8]
  float* bias  = (float*)(smem + BIAS_OFF);   // [32]

  const int cu = blockIdx.x;
  const int layer = cu >> 7;
  const int lcu = cu & 127;
  const int U0 = lcu * 8;
  const int K2 = layer ? 4096 : 3072;         // bytes per LDS weight column
  const int tid = threadIdx.x;

  // ---- startup: pack this CU's 32 weight columns (bf16, k-byte XOR swizzle) ----
  for (int n = 0; n < 32; ++n) {
    const int grow = (n >> 3) * 1024 + U0 + (n & 7);
    char* colbase = smem + n * K2;
    const u32 swn = (u32)(n & 15) << 6;
    if (!layer) {
      const float* rih = wih0 + (size_t)grow * 512;
      const float* rhh = whh0 + (size_t)grow * 1024;
      for (int k = tid; k < 1536; k += 256) {
        float v = (k < 512) ? rih[k] : rhh[k - 512];
        *(u16*)(colbase + (((u32)k * 2u) ^ swn)) = f2bf(v);
      }
    } else {
      const float* rih = wih1 + (size_t)grow * 1024;
      const float* rhh = whh1 + (size_t)grow * 1024;
      for (int k = tid; k < 2048; k += 256) {
        float v = (k < 1024) ? rih[k] : rhh[k - 1024];
        *(u16*)(colbase + (((u32)k * 2u) ^ swn)) = f2bf(v);
      }
    }
  }
  if (tid < 32) {
    int grow = (tid >> 3) * 1024 + U0 + (tid & 7);
    bias[tid] = layer ? (bih1[grow] + bhh1[grow]) : (bih0[grow] + bhh0[grow]);
  }
  for (int i = tid; i < 512; i += 256) cst[i] = 0.0f;
  for (int i = tid; i < 2048; i += 256) gates[i] = 0.0f;
  __syncthreads();

  const int lane = tid & 63;
  const int wave = tid >> 6;
  const int lr = lane & 15;
  const int lkel = (lane >> 4) * 8;
  const u32 sw = (u32)lr << 6;
  const char* wrow0 = smem + (size_t)lr * K2;
  const char* wrow1 = smem + (size_t)(16 + lr) * K2;

  // this wave's 32 producer flags: c = 4*wave + 16*(l>>2) + (l&3), l = lane&31
  const u32 myc = (u32)(4 * wave + 16 * ((lane & 31) >> 2) + (lane & 3));

  // per-wave wait until this wave's 32 producer flags all >= target (no barrier)
  auto wpoll = [&](const u32* fbase, u32 target) {
    const u32* p = fbase + myc * 32u;
    for (;;) {
      u32 v = load_sc01(p);
      if (__all((int)(v >= target))) break;
      __builtin_amdgcn_s_sleep(2);
    }
  };

  for (int t = 0; t < 512; ++t) {
    f32x4 z = {0.0f, 0.0f, 0.0f, 0.0f};
    f32x4 acc[4][2];
    #pragma unroll
    for (int a = 0; a < 4; ++a) { acc[a][0] = z; acc[a][1] = z; }

    // strided A (x panel [b][i])
    auto do_tile_x = [&](const u16* Abase, int strideA, int kk, int k0) {
      const u16* ap = Abase + (size_t)lr * strideA + kk + lkel;
      short8 a0 = *(const short8*)(ap);
      short8 a1 = *(const short8*)(ap + 16 * strideA);
      short8 a2 = *(const short8*)(ap + 32 * strideA);
      short8 a3 = *(const short8*)(ap + 48 * strideA);
      const u32 kb = ((u32)(k0 + lkel) * 2u) ^ sw;
      short8 b0 = *(const short8*)(wrow0 + kb);
      short8 b1 = *(const short8*)(wrow1 + kb);
      acc[0][0] = __builtin_amdgcn_mfma_f32_16x16x32_bf16(a0, b0, acc[0][0], 0, 0, 0);
      acc[1][0] = __builtin_amdgcn_mfma_f32_16x16x32_bf16(a1, b0, acc[1][0], 0, 0, 0);
      acc[2][0] = __builtin_amdgcn_mfma_f32_16x16x32_bf16(a2, b0, acc[2][0], 0, 0, 0);
      acc[3][0] = __builtin_amdgcn_mfma_f32_16x16x32_bf16(a3, b0, acc[3][0], 0, 0, 0);
      acc[0][1] = __builtin_amdgcn_mfma_f32_16x16x32_bf16(a0, b1, acc[0][1], 0, 0, 0);
      acc[1][1] = __builtin_amdgcn_mfma_f32_16x16x32_bf16(a1, b1, acc[1][1], 0, 0, 0);
      acc[2][1] = __builtin_amdgcn_mfma_f32_16x16x32_bf16(a2, b1, acc[2][1], 0, 0, 0);
      acc[3][1] = __builtin_amdgcn_mfma_f32_16x16x32_bf16(a3, b1, acc[3][1], 0, 0, 0);
    };
    // chunked A (h panel [c][b][u]); c_base = first producer chunk of this k-tile
    auto do_tile_h = [&](const u16* Hbase, int c_base, int k0) {
      const u16* ap = Hbase + ((size_t)(c_base + (lane >> 4)) << 9) + (size_t)lr * 8;
      short8 a0 = *(const short8*)(ap);
      short8 a1 = *(const short8*)(ap + 128);
      short8 a2 = *(const short8*)(ap + 256);
      short8 a3 = *(const short8*)(ap + 384);
      const u32 kb = ((u32)(k0 + lkel) * 2u) ^ sw;
      short8 b0 = *(const short8*)(wrow0 + kb);
      short8 b1 = *(const short8*)(wrow1 + kb);
      acc[0][0] = __builtin_amdgcn_mfma_f32_16x16x32_bf16(a0, b0, acc[0][0], 0, 0, 0);
      acc[1][0] = __builtin_amdgcn_mfma_f32_16x16x32_bf16(a1, b0, acc[1][0], 0, 0, 0);
      acc[2][0] = __builtin_amdgcn_mfma_f32_16x16x32_bf16(a2, b0, acc[2][0], 0, 0, 0);
      acc[3][0] = __builtin_amdgcn_mfma_f32_16x16x32_bf16(a3, b0, acc[3][0], 0, 0, 0);
      acc[0][1] = __builtin_amdgcn_mfma_f32_16x16x32_bf16(a0, b1, acc[0][1], 0, 0, 0);
      acc[1][1] = __builtin_amdgcn_mfma_f32_16x16x32_bf16(a1, b1, acc[1][1], 0, 0, 0);
      acc[2][1] = __builtin_amdgcn_mfma_f32_16x16x32_bf16(a2, b1, acc[2][1], 0, 0, 0);
      acc[3][1] = __builtin_amdgcn_mfma_f32_16x16x32_bf16(a3, b1, acc[3][1], 0, 0, 0);
    };

    if (!layer) {
      const u16* Ax = xb + (size_t)t * 32768;
      #pragma unroll
      for (int j = 0; j < 4; ++j) {
        int k0 = (wave + 4 * j) * 32;
        do_tile_x(Ax, 512, k0, k0);
      }
      if (t > 0) {
        wpoll(f0, (u32)t);
        const u16* Hs = h0h + (size_t)t * 65536;       // h0[t-1]
        #pragma unroll
        for (int j = 4; j < 12; ++j) {
          int k0 = (wave + 4 * j) * 32;
          do_tile_h(Hs, (k0 - 512) >> 3, k0);
        }
      }
    } else {
      if (t > 0) {
        wpoll(f1, (u32)t);
        const u16* H1s = h1h + (size_t)t * 65536;      // h1[t-1]
        #pragma unroll
        for (int j = 8; j < 16; ++j) {
          int k0 = (wave + 4 * j) * 32;
          do_tile_h(H1s, (k0 - 1024) >> 3, k0);
        }
      }
      wpoll(f0, (u32)(t + 1));
      const u16* H0s = h0h + (size_t)(t + 1) * 65536;  // h0[t]
      #pragma unroll
      for (int j = 0; j < 8; ++j) {
        int k0 = (wave + 4 * j) * 32;
        do_tile_h(H0s, k0 >> 3, k0);
      }
    }

    // K-split reduction across 4 waves via LDS float atomics
    #pragma unroll
    for (int mt = 0; mt < 4; ++mt)
      #pragma unroll
      for (int nt = 0; nt < 2; ++nt)
        #pragma unroll
        for (int r = 0; r < 4; ++r) {
          int row = mt * 16 + (lane >> 4) * 4 + r;   // batch
          int col = nt * 16 + lr;                    // local gate col
          atomicAdd(&gates[row * 32 + col], acc[mt][nt][r]);
        }
    __syncthreads();

    { // nonlinearity + state; each thread re-zeros its own gate slots after reading
      const int b = tid >> 2;
      const int ub = (tid & 3) * 2;
      float hv[2];
      #pragma unroll
      for (int du = 0; du < 2; ++du) {
        const int u = ub + du;
        float gi = gates[b * 32 + u];       gates[b * 32 + u] = 0.0f;
        float gf = gates[b * 32 + 8 + u];   gates[b * 32 + 8 + u] = 0.0f;
        float gg = gates[b * 32 + 16 + u];  gates[b * 32 + 16 + u] = 0.0f;
        float go = gates[b * 32 + 24 + u];  gates[b * 32 + 24 + u] = 0.0f;
        gi += bias[u]; gf += bias[8 + u]; gg += bias[16 + u]; go += bias[24 + u];
        float ii = 1.0f / (1.0f + __expf(-gi));
        float ff = 1.0f / (1.0f + __expf(-gf));
        float g2 = 1.0f - 2.0f / (__expf(2.0f * gg) + 1.0f);
        float oo = 1.0f / (1.0f + __expf(-go));
        float c = ff * cst[b * 8 + u] + ii * g2;
        cst[b * 8 + u] = c;
        hv[du] = oo * (1.0f - 2.0f / (__expf(2.0f * c) + 1.0f));
      }
      u32 packed = (u32)f2bf(hv[0]) | ((u32)f2bf(hv[1]) << 16);
      u16* hist = layer ? h1h : h0h;
      // [t+1][lcu][b][u]: thread tid's u32 sits at block_base + tid*4 (coalesced 1KB)
      u32* dst = (u32*)(hist + (size_t)(t + 1) * 65536 + ((size_t)lcu << 9)) + tid;
      store_sc01(dst, packed);
    }
    asm volatile("s_waitcnt vmcnt(0)" ::: "memory");  // h block ack'd at coherence pt
    __syncthreads();                                  // all waves drained
    if (tid == 0) {
      u32* fl = (layer ? f1 : f0) + (u32)lcu * 32u;
      store_sc01(fl, (u32)(t + 1));                   // publish step t done
    }
  }

  // FC + softmax epilogue on block 0 (reads h1[511] = slot 512, layout [c][b][u])
  if (cu == 0) {
    if (wave == 0) {                // generic poll: lanes cover 128 flags, 2 each
      #pragma unroll
      for (int j = 0; j < 2; ++j) {
        const u32* p = f1 + (u32)(lane + 64 * j) * 32u;
        while (load_sc01(p) < 512u) __builtin_amdgcn_s_sleep(2);
      }
    }
    __syncthreads();
    if (tid < 128) {
      const int b = tid >> 1, cls = tid & 1;
      const u16* hbase = h1h + (size_t)512 * 65536;
      const float* w = fc_w + (size_t)cls * 1024;
      float sum = fc_b[cls];
      for (int c = 0; c < 128; ++c) {
        short8 hvv = *(const short8*)(hbase + ((size_t)c << 9) + (size_t)b * 8);
        #pragma unroll
        for (int e = 0; e < 8; ++e) sum += bf2f((u16)hvv[e]) * w[c * 8 + e];
      }
      float other = __shfl_xor(sum, 1);
      float mx = fmaxf(sum, other);
      float e0 = __expf(sum - mx), e1 = __expf(other - mx);
      out[b * 2 + cls] = e0 / (e0 + e1);
    }
  }
}

extern "C" void kernel_launch(void* const* d_in, const int* in_sizes, int n_in,
                              void* d_out, int out_size, void* d_ws, size_t ws_size,
                              hipStream_t stream) {
  const float* x    = (const float*)d_in[0];
  const float* wih0 = (const float*)d_in[1];
  const float* whh0 = (const float*)d_in[2];
  const float* bih0 = (const float*)d_in[3];
  const float* bhh0 = (const float*)d_in[4];
  const float* wih1 = (const float*)d_in[5];
  const float* whh1 = (const float*)d_in[6];
  const float* bih1 = (const float*)d_in[7];
  const float* bhh1 = (const float*)d_in[8];
  const float* fcw  = (const float*)d_in[9];
  const float* fcb  = (const float*)d_in[10];
  float* out = (float*)d_out;
  char* ws = (char*)d_ws;

  u16* xb  = (u16*)(ws + XB_OFF);
  u16* h0h = (u16*)(ws + H0_OFF);
  u16* h1h = (u16*)(ws + H1_OFF);
  u32* f0  = (u32*)(ws + F0_OFF);
  u32* f1  = (u32*)(ws + F1_OFF);

  (void)hipFuncSetAttribute((const void*)lstm_persist,
      hipFuncAttributeMaxDynamicSharedMemorySize, LDS_TOTAL);

  hipMemsetAsync(ws + F0_OFF, 0, FLAGS_LEN, stream);   // zero step flags
  prep_x<<<8192, 256, 0, stream>>>(x, xb);
  lstm_persist<<<256, 256, LDS_TOTAL, stream>>>(
      (const u16*)xb, wih0, whh0, bih0, bhh0, wih1, whh1, bih1, bhh1,
      h0h, h1h, f0, f1, fcw, fcb, out);
}

// Round 5
// 8118.742 us; speedup vs baseline: 2.4262x; 1.0540x over previous
//
#include <hip/hip_runtime.h>

typedef __attribute__((ext_vector_type(8))) short short8;
typedef __attribute__((ext_vector_type(4))) float f32x4;
typedef unsigned short u16;
typedef unsigned int u32;

// ---------------- workspace layout (bytes) ----------------
// xb:  [512][64][512] bf16                          = 33,554,432
// h0h: [513][128 cu][64 b][8 u] bf16 (slot t+1=h[t])= 67,239,936
// h1h: same                                          = 67,239,936
// f0/f1: [128] monotonic step flags, 128B apart      = 16,384 each
#define XB_OFF 0ul
#define H0_OFF 33554432ul
#define H1_OFF 100794368ul
#define F0_OFF 168034304ul
#define F1_OFF 168050688ul
#define FLAGS_LEN 32768ul

// ---------------- LDS layout (bytes) ----------------
#define WB_MAX    131072                  // 32 cols * 2*K bytes (K=2048 for L1)
#define GATES_OFF WB_MAX                  // [64][33] f32 = 8448 (pad vs bank conflicts)
#define CST_OFF   (WB_MAX + 8448)         // [64][8]  f32 = 2048
#define BIAS_OFF  (WB_MAX + 8448 + 2048)  // [32] f32 = 128
#define LDS_TOTAL (WB_MAX + 8448 + 2048 + 128)   // 141696 <= 163840

__device__ __forceinline__ u16 f2bf(float f) {
  u32 u = __float_as_uint(f);
  return (u16)((u + 0x7fffu + ((u >> 16) & 1u)) >> 16);   // RNE
}
__device__ __forceinline__ float bf2f(u16 s) { return __uint_as_float(((u32)s) << 16); }

__device__ __forceinline__ u32 load_sc01(const u32* p) {
  u32 v;
  asm volatile("global_load_dword %0, %1, off sc0 sc1\n\ts_waitcnt vmcnt(0)"
               : "=v"(v) : "v"(p) : "memory");
  return v;
}
__device__ __forceinline__ void store_sc01(u32* p, u32 v) {
  asm volatile("global_store_dword %0, %1, off sc0 sc1" :: "v"(p), "v"(v) : "memory");
}

// x[b][t][i] fp32 -> xb[t][b][i] bf16
__global__ __launch_bounds__(256) void prep_x(const float* __restrict__ x,
                                              u16* __restrict__ xb) {
  u32 stride = gridDim.x * blockDim.x;
  for (u32 e = blockIdx.x * blockDim.x + threadIdx.x; e < 16777216u; e += stride) {
    u32 i = e & 511u, b = (e >> 9) & 63u, t = e >> 15;
    xb[e] = f2bf(x[((size_t)b << 18) + ((size_t)t << 9) + i]);
  }
}

// Persistent kernel, 256 blocks (1/CU). Blocks 0..127: layer0 (K=1536 = [x|h0prev]).
// Blocks 128..255: layer1 (K=2048 = [h0cur|h1prev]).
// Per step: issue ALL A-fragment loads into registers first (deep VMEM pipeline,
// ~32-48 loads in flight), then the MFMA sweep; per-wave flag polls overlap flight.
__global__ __launch_bounds__(256, 1) void lstm_persist(
    const u16* __restrict__ xb,
    const float* __restrict__ wih0, const float* __restrict__ whh0,
    const float* __restrict__ bih0, const float* __restrict__ bhh0,
    const float* __restrict__ wih1, const float* __restrict__ whh1,
    const float* __restrict__ bih1, const float* __restrict__ bhh1,
    u16* __restrict__ h0h, u16* __restrict__ h1h,
    u32* __restrict__ f0, u32* __restrict__ f1,
    const float* __restrict__ fc_w, const float* __restrict__ fc_b,
    float* __restrict__ out) {
  extern __shared__ char smem[];
  float* gates = (float*)(smem + GATES_OFF);  // [64][33]
  float* cst   = (float*)(smem + CST_OFF);    // [64][8]
  float* bias  = (float*)(smem + BIAS_OFF);   // [32]

  const int cu = blockIdx.x;
  const int layer = cu >> 7;
  const int lcu = cu & 127;
  const int U0 = lcu * 8;
  const int K2 = layer ? 4096 : 3072;         // bytes per LDS weight column
  const int tid = threadIdx.x;

  // ---- startup: pack weight columns; swizzle (n&7)<<4 -> even 16B bank-slot spread
  for (int n = 0; n < 32; ++n) {
    const int grow = (n >> 3) * 1024 + U0 + (n & 7);
    char* colbase = smem + n * K2;
    const u32 swn = (u32)(n & 7) << 4;
    if (!layer) {
      const float* rih = wih0 + (size_t)grow * 512;
      const float* rhh = whh0 + (size_t)grow * 1024;
      for (int k = tid; k < 1536; k += 256) {
        float v = (k < 512) ? rih[k] : rhh[k - 512];
        *(u16*)(colbase + (((u32)k * 2u) ^ swn)) = f2bf(v);
      }
    } else {
      const float* rih = wih1 + (size_t)grow * 1024;
      const float* rhh = whh1 + (size_t)grow * 1024;
      for (int k = tid; k < 2048; k += 256) {
        float v = (k < 1024) ? rih[k] : rhh[k - 1024];
        *(u16*)(colbase + (((u32)k * 2u) ^ swn)) = f2bf(v);
      }
    }
  }
  if (tid < 32) {
    int grow = (tid >> 3) * 1024 + U0 + (tid & 7);
    bias[tid] = layer ? (bih1[grow] + bhh1[grow]) : (bih0[grow] + bhh0[grow]);
  }
  for (int i = tid; i < 512; i += 256) cst[i] = 0.0f;
  for (int i = tid; i < 2112; i += 256) gates[i] = 0.0f;
  __syncthreads();

  const int lane = tid & 63;
  const int wave = tid >> 6;
  const int lr = lane & 15;
  const int lq = lane >> 4;
  const int lkel = lq * 8;
  const u32 swz = (u32)(lr & 7) << 4;
  const char* wrow0 = smem + (size_t)lr * K2;
  const char* wrow1 = smem + (size_t)(16 + lr) * K2;

  // this wave's 32 producer flags: c = 4*wave + 16*((lane&31)>>2) + (lane&3)
  const u32 myc = (u32)(4 * wave + 16 * ((lane & 31) >> 2) + (lane & 3));

  auto wpoll = [&](const u32* fbase, u32 target) {
    const u32* p = fbase + myc * 32u;
    for (;;) {
      u32 v = load_sc01(p);
      if (__all((int)(v >= target))) break;
      __builtin_amdgcn_s_sleep(1);
    }
  };

  for (int t = 0; t < 512; ++t) {
    f32x4 z = {0.0f, 0.0f, 0.0f, 0.0f};
    f32x4 acc[4][2];
    #pragma unroll
    for (int a = 0; a < 4; ++a) { acc[a][0] = z; acc[a][1] = z; }

    short8 A[12][4];           // A-fragment register file (SROA'd; static idx only)

    // issue loads ------------------------------------------------------------
    auto load_x = [&](int s, const u16* Abase, int k0) {
      const u16* ap = Abase + (size_t)lr * 512 + k0 + lkel;
      A[s][0] = *(const short8*)(ap);
      A[s][1] = *(const short8*)(ap + 16 * 512);
      A[s][2] = *(const short8*)(ap + 32 * 512);
      A[s][3] = *(const short8*)(ap + 48 * 512);
    };
    auto load_h = [&](int s, const u16* Hbase, int c_base) {
      const u16* ap = Hbase + ((size_t)(c_base + lq) << 9) + (size_t)lr * 8;
      A[s][0] = *(const short8*)(ap);
      A[s][1] = *(const short8*)(ap + 128);
      A[s][2] = *(const short8*)(ap + 256);
      A[s][3] = *(const short8*)(ap + 384);
    };
    auto mfma_tile = [&](int s, int k0) {
      const u32 kb = ((u32)(k0 + lkel) * 2u) ^ swz;
      short8 b0 = *(const short8*)(wrow0 + kb);
      short8 b1 = *(const short8*)(wrow1 + kb);
      acc[0][0] = __builtin_amdgcn_mfma_f32_16x16x32_bf16(A[s][0], b0, acc[0][0], 0, 0, 0);
      acc[1][0] = __builtin_amdgcn_mfma_f32_16x16x32_bf16(A[s][1], b0, acc[1][0], 0, 0, 0);
      acc[2][0] = __builtin_amdgcn_mfma_f32_16x16x32_bf16(A[s][2], b0, acc[2][0], 0, 0, 0);
      acc[3][0] = __builtin_amdgcn_mfma_f32_16x16x32_bf16(A[s][3], b0, acc[3][0], 0, 0, 0);
      acc[0][1] = __builtin_amdgcn_mfma_f32_16x16x32_bf16(A[s][0], b1, acc[0][1], 0, 0, 0);
      acc[1][1] = __builtin_amdgcn_mfma_f32_16x16x32_bf16(A[s][1], b1, acc[1][1], 0, 0, 0);
      acc[2][1] = __builtin_amdgcn_mfma_f32_16x16x32_bf16(A[s][2], b1, acc[2][1], 0, 0, 0);
      acc[3][1] = __builtin_amdgcn_mfma_f32_16x16x32_bf16(A[s][3], b1, acc[3][1], 0, 0, 0);
    };

    if (!layer) {
      const u16* Ax = xb + (size_t)t * 32768;
      #pragma unroll
      for (int j = 0; j < 4; ++j) load_x(j, Ax, (wave + 4 * j) * 32);
      if (t > 0) {
        wpoll(f0, (u32)t);
        const u16* Hs = h0h + (size_t)t * 65536;       // h0[t-1]
        #pragma unroll
        for (int j = 4; j < 12; ++j) load_h(j, Hs, 4 * wave + 16 * (j - 4));
      }
      #pragma unroll
      for (int j = 0; j < 4; ++j) mfma_tile(j, (wave + 4 * j) * 32);
      if (t > 0) {
        #pragma unroll
        for (int j = 4; j < 12; ++j) mfma_tile(j, (wave + 4 * j) * 32);
      }
    } else {
      if (t > 0) {
        wpoll(f1, (u32)t);
        const u16* H1s = h1h + (size_t)t * 65536;      // h1[t-1]
        #pragma unroll
        for (int j = 0; j < 8; ++j) load_h(j, H1s, 4 * wave + 16 * j);
      }
      wpoll(f0, (u32)(t + 1));
      const u16* H0s = h0h + (size_t)(t + 1) * 65536;  // h0[t]
      #pragma unroll
      for (int j = 0; j < 4; ++j) load_h(8 + j, H0s, 4 * wave + 16 * j);
      if (t > 0) {
        #pragma unroll
        for (int j = 0; j < 8; ++j) mfma_tile(j, (wave + 4 * (8 + j)) * 32);
      }
      #pragma unroll
      for (int j = 0; j < 4; ++j) load_h(j, H0s, 4 * wave + 16 * (4 + j));  // reuse slots
      #pragma unroll
      for (int j = 0; j < 4; ++j) mfma_tile(8 + j, (wave + 4 * j) * 32);
      #pragma unroll
      for (int j = 0; j < 4; ++j) mfma_tile(j, (wave + 4 * (4 + j)) * 32);
    }

    // K-split reduction across 4 waves via LDS float atomics (stride 33: ~2-way)
    #pragma unroll
    for (int mt = 0; mt < 4; ++mt)
      #pragma unroll
      for (int nt = 0; nt < 2; ++nt)
        #pragma unroll
        for (int r = 0; r < 4; ++r) {
          int row = mt * 16 + lq * 4 + r;              // batch
          int col = nt * 16 + lr;                      // local gate col
          atomicAdd(&gates[row * 33 + col], acc[mt][nt][r]);
        }
    __syncthreads();

    { // nonlinearity + state; each thread re-zeros its own gate slots after reading
      const int b = tid >> 2;
      const int ub = (tid & 3) * 2;
      float hv[2];
      #pragma unroll
      for (int du = 0; du < 2; ++du) {
        const int u = ub + du;
        float gi = gates[b * 33 + u];       gates[b * 33 + u] = 0.0f;
        float gf = gates[b * 33 + 8 + u];   gates[b * 33 + 8 + u] = 0.0f;
        float gg = gates[b * 33 + 16 + u];  gates[b * 33 + 16 + u] = 0.0f;
        float go = gates[b * 33 + 24 + u];  gates[b * 33 + 24 + u] = 0.0f;
        gi += bias[u]; gf += bias[8 + u]; gg += bias[16 + u]; go += bias[24 + u];
        float ii = 1.0f / (1.0f + __expf(-gi));
        float ff = 1.0f / (1.0f + __expf(-gf));
        float g2 = 1.0f - 2.0f / (__expf(2.0f * gg) + 1.0f);
        float oo = 1.0f / (1.0f + __expf(-go));
        float c = ff * cst[b * 8 + u] + ii * g2;
        cst[b * 8 + u] = c;
        hv[du] = oo * (1.0f - 2.0f / (__expf(2.0f * c) + 1.0f));
      }
      u32 packed = (u32)f2bf(hv[0]) | ((u32)f2bf(hv[1]) << 16);
      u16* hist = layer ? h1h : h0h;
      u32* dst = (u32*)(hist + (size_t)(t + 1) * 65536 + ((size_t)lcu << 9)) + tid;
      store_sc01(dst, packed);
    }
    asm volatile("s_waitcnt vmcnt(0)" ::: "memory");  // h block ack'd at coherence pt
    __syncthreads();                                  // all waves drained
    if (tid == 0) {
      u32* fl = (layer ? f1 : f0) + (u32)lcu * 32u;
      store_sc01(fl, (u32)(t + 1));                   // publish step t done
    }
  }

  // FC + softmax epilogue on block 0 (reads h1[511] = slot 512, layout [c][b][u])
  if (cu == 0) {
    if (wave == 0) {                // lanes cover 128 flags, 2 each
      #pragma unroll
      for (int j = 0; j < 2; ++j) {
        const u32* p = f1 + (u32)(lane + 64 * j) * 32u;
        while (load_sc01(p) < 512u) __builtin_amdgcn_s_sleep(1);
      }
    }
    __syncthreads();
    if (tid < 128) {
      const int b = tid >> 1, cls = tid & 1;
      const u16* hbase = h1h + (size_t)512 * 65536;
      const float* w = fc_w + (size_t)cls * 1024;
      float sum = fc_b[cls];
      for (int c = 0; c < 128; ++c) {
        short8 hvv = *(const short8*)(hbase + ((size_t)c << 9) + (size_t)b * 8);
        #pragma unroll
        for (int e = 0; e < 8; ++e) sum += bf2f((u16)hvv[e]) * w[c * 8 + e];
      }
      float other = __shfl_xor(sum, 1);
      float mx = fmaxf(sum, other);
      float e0 = __expf(sum - mx), e1 = __expf(other - mx);
      out[b * 2 + cls] = e0 / (e0 + e1);
    }
  }
}

extern "C" void kernel_launch(void* const* d_in, const int* in_sizes, int n_in,
                              void* d_out, int out_size, void* d_ws, size_t ws_size,
                              hipStream_t stream) {
  const float* x    = (const float*)d_in[0];
  const float* wih0 = (const float*)d_in[1];
  const float* whh0 = (const float*)d_in[2];
  const float* bih0 = (const float*)d_in[3];
  const float* bhh0 = (const float*)d_in[4];
  const float* wih1 = (const float*)d_in[5];
  const float* whh1 = (const float*)d_in[6];
  const float* bih1 = (const float*)d_in[7];
  const float* bhh1 = (const float*)d_in[8];
  const float* fcw  = (const float*)d_in[9];
  const float* fcb  = (const float*)d_in[10];
  float* out = (float*)d_out;
  char* ws = (char*)d_ws;

  u16* xb  = (u16*)(ws + XB_OFF);
  u16* h0h = (u16*)(ws + H0_OFF);
  u16* h1h = (u16*)(ws + H1_OFF);
  u32* f0  = (u32*)(ws + F0_OFF);
  u32* f1  = (u32*)(ws + F1_OFF);

  (void)hipFuncSetAttribute((const void*)lstm_persist,
      hipFuncAttributeMaxDynamicSharedMemorySize, LDS_TOTAL);

  hipMemsetAsync(ws + F0_OFF, 0, FLAGS_LEN, stream);   // zero step flags
  prep_x<<<8192, 256, 0, stream>>>(x, xb);
  lstm_persist<<<256, 256, LDS_TOTAL, stream>>>(
      (const u16*)xb, wih0, whh0, bih0, bhh0, wih1, whh1, bih1, bhh1,
      h0h, h1h, f0, f1, fcw, fcb, out);
}